// Round 2
// baseline (339.421 us; speedup 1.0000x reference)
//
#include <hip/hip_runtime.h>
#include <math.h>

// LinearAttention: out[n,l,h,m] = (phi(Q[l])·KV[:,m]) / (phi(Q[l])·Ksum + eps)
//   KV[d][m] = sum_s phi(K[s,d]) V[s,m],  Ksum[d] = sum_s phi(K[s,d])
//   phi(x) = elu(x)+1 = x>0 ? x+1 : exp(x)

#define N_B 8
#define S_LEN 8192
#define H_N 8
#define D_DIM 64
#define NH (N_B * H_N)
#define EPS 1e-6f
#define ROWSTRIDE (H_N * D_DIM)   // 512 floats between consecutive s rows

__device__ __forceinline__ float felu1(float x) {
    return x > 0.0f ? x + 1.0f : __expf(x);
}

// ---------------- Phase 1a: one WAVE per (nh, chunk) ----------------
// Lane d holds phi(K[s,d]) (coalesced 256B load); V row is wave-uniform
// (broadcast load). acc[64] lives in VGPRs. No LDS, no barriers.
__global__ __launch_bounds__(256, 4) void kv_partial_kernel(
        const float* __restrict__ Kin, const float* __restrict__ Vin,
        float* __restrict__ kvp,   // [NH*nchunk][64*64]
        float* __restrict__ ksp,   // [NH*nchunk][64]
        int nchunk) {
    const int wid  = __builtin_amdgcn_readfirstlane(threadIdx.x >> 6);
    const int lane = threadIdx.x & 63;
    const int gw   = blockIdx.x * 4 + wid;       // global wave id = (nh, chunk)
    const int nh   = gw / nchunk;
    const int c    = gw - nh * nchunk;
    const int n_i  = nh >> 3, h_i = nh & 7;
    const int rows = S_LEN / nchunk;
    const int s0   = c * rows;

    const float* Kb = Kin + (size_t)n_i * S_LEN * ROWSTRIDE + (size_t)h_i * D_DIM;
    const float* Vb = Vin + (size_t)n_i * S_LEN * ROWSTRIDE + (size_t)h_i * D_DIM;

    float acc[64];
    #pragma unroll
    for (int m = 0; m < 64; ++m) acc[m] = 0.0f;
    float ksum = 0.0f;

    #pragma unroll 2
    for (int s = s0; s < s0 + rows; ++s) {
        const float kraw = Kb[(size_t)s * ROWSTRIDE + lane];
        const float kphi = felu1(kraw);
        ksum += kphi;
        const float4* Vr = (const float4*)(Vb + (size_t)s * ROWSTRIDE);
        #pragma unroll
        for (int m4 = 0; m4 < 16; ++m4) {
            const float4 v = Vr[m4];             // wave-uniform address
            acc[4 * m4 + 0] += kphi * v.x;
            acc[4 * m4 + 1] += kphi * v.y;
            acc[4 * m4 + 2] += kphi * v.z;
            acc[4 * m4 + 3] += kphi * v.w;
        }
    }

    float* kvo = kvp + (size_t)gw * (D_DIM * D_DIM) + (size_t)lane * D_DIM;
    #pragma unroll
    for (int m4 = 0; m4 < 16; ++m4) {
        float4 o;
        o.x = acc[4 * m4 + 0]; o.y = acc[4 * m4 + 1];
        o.z = acc[4 * m4 + 2]; o.w = acc[4 * m4 + 3];
        ((float4*)kvo)[m4] = o;
    }
    ksp[(size_t)gw * D_DIM + lane] = ksum;
}

// ---------------- Phase 1b: reduce partials -> final KV, Ksum ----------------
// grid = NH*16 blocks; block (nh, eb) sums 256 elements of KV over chunks.
__global__ __launch_bounds__(256) void kv_reduce_kernel(
        const float* __restrict__ kvp, const float* __restrict__ ksp,
        float* __restrict__ KV, float* __restrict__ Ksum, int nchunk) {
    const int nh = blockIdx.x >> 4;
    const int eb = blockIdx.x & 15;
    const int t  = threadIdx.x;
    const int e  = eb * 256 + t;
    float s = 0.0f;
    const float* base = kvp + (size_t)nh * nchunk * (D_DIM * D_DIM) + e;
    for (int c = 0; c < nchunk; ++c)
        s += base[(size_t)c * (D_DIM * D_DIM)];
    KV[(size_t)nh * (D_DIM * D_DIM) + e] = s;
    if (eb == 0 && t < D_DIM) {
        float ks = 0.0f;
        const float* kb = ksp + (size_t)nh * nchunk * D_DIM + t;
        for (int c = 0; c < nchunk; ++c) ks += kb[(size_t)c * D_DIM];
        Ksum[(size_t)nh * D_DIM + t] = ks;
    }
}

// ---------------- Phase 2: out = (Q·KV) / (Q·Ksum + eps) ----------------
// 256 threads: thread = (rg = t>>3 -> 4 rows, mg = t&7 -> 8 m). RPB=128 rows.
// Register tile 4x8 cuts LDS traffic ~2.2x vs 1x4. One barrier per block.
__global__ __launch_bounds__(256) void out_kernel(
        const float* __restrict__ Qin, const float* __restrict__ KV,
        const float* __restrict__ Ksum, float* __restrict__ Out) {
    constexpr int RPB  = 128;
    constexpr int QPAD = 68;
    __shared__ __align__(16) float KVs[D_DIM][D_DIM];   // 16 KB
    __shared__ __align__(16) float Kss[D_DIM];
    __shared__ __align__(16) float Qs[RPB][QPAD];       // 34.8 KB, XOR-swizzled cols

    const int b    = blockIdx.x;
    const int nblk = S_LEN / RPB;          // 64
    const int nh   = b / nblk;
    const int rb   = b - nh * nblk;
    const int n_i  = nh >> 3, h_i = nh & 7;
    const int t    = threadIdx.x;

    const float* Qb = Qin + (size_t)n_i * S_LEN * ROWSTRIDE + (size_t)h_i * D_DIM;
    float*       Ob = Out + (size_t)n_i * S_LEN * ROWSTRIDE + (size_t)h_i * D_DIM;

    // stage KV + Ksum (vectorized)
    {
        const float4* src = (const float4*)(KV + (size_t)nh * (D_DIM * D_DIM));
        float4* dst = (float4*)(&KVs[0][0]);
        #pragma unroll
        for (int i = 0; i < 4; ++i) dst[t + 256 * i] = src[t + 256 * i];
        if (t < 16) ((float4*)Kss)[t] = ((const float4*)(Ksum + (size_t)nh * D_DIM))[t];
    }

    // stage Q rows (feature-mapped), cols XOR-swizzled by ((row>>2)&7)<<2
    const int ltx = t & 15, lty = t >> 4;
    const int sbase = rb * RPB;
    #pragma unroll
    for (int i = 0; i < 8; ++i) {
        const int row = lty + 16 * i;
        const float4 q = *(const float4*)(Qb + (size_t)(sbase + row) * ROWSTRIDE + ltx * 4);
        float4 f;
        f.x = felu1(q.x); f.y = felu1(q.y); f.z = felu1(q.z); f.w = felu1(q.w);
        const int pc = (ltx * 4) ^ (((row >> 2) & 7) << 2);
        *(float4*)&Qs[row][pc] = f;
    }
    __syncthreads();

    const int rg = t >> 3;                 // 0..31 -> rows rg*4..rg*4+3
    const int mg = t & 7;                  // 0..7  -> cols mg*8..mg*8+7
    const int r0 = rg * 4, m0 = mg * 8;
    const int sw = ((rg & 7) << 2);        // (row>>2)&7 == rg&7 for all 4 rows

    float acc[4][8];
    float zz[4];
    #pragma unroll
    for (int r = 0; r < 4; ++r) {
        zz[r] = 0.0f;
        #pragma unroll
        for (int m = 0; m < 8; ++m) acc[r][m] = 0.0f;
    }

    #pragma unroll
    for (int d0 = 0; d0 < D_DIM; d0 += 4) {
        const float4 ks4 = *(const float4*)&Kss[d0];       // uniform broadcast
        float4 qr[4];
        #pragma unroll
        for (int r = 0; r < 4; ++r) {
            qr[r] = *(const float4*)&Qs[r0 + r][d0 ^ sw];
            zz[r] += qr[r].x * ks4.x + qr[r].y * ks4.y
                   + qr[r].z * ks4.z + qr[r].w * ks4.w;
        }
        #pragma unroll
        for (int j = 0; j < 4; ++j) {
            const float4 kva = *(const float4*)&KVs[d0 + j][m0];
            const float4 kvb = *(const float4*)&KVs[d0 + j][m0 + 4];
            #pragma unroll
            for (int r = 0; r < 4; ++r) {
                const float q = (&qr[r].x)[j];   // static (r,j unrolled)
                acc[r][0] += q * kva.x; acc[r][1] += q * kva.y;
                acc[r][2] += q * kva.z; acc[r][3] += q * kva.w;
                acc[r][4] += q * kvb.x; acc[r][5] += q * kvb.y;
                acc[r][6] += q * kvb.z; acc[r][7] += q * kvb.w;
            }
        }
    }

    #pragma unroll
    for (int r = 0; r < 4; ++r) {
        const float z = 1.0f / (zz[r] + EPS);
        float4 o1, o2;
        o1.x = acc[r][0] * z; o1.y = acc[r][1] * z;
        o1.z = acc[r][2] * z; o1.w = acc[r][3] * z;
        o2.x = acc[r][4] * z; o2.y = acc[r][5] * z;
        o2.z = acc[r][6] * z; o2.w = acc[r][7] * z;
        float* op = Ob + (size_t)(sbase + r0 + r) * ROWSTRIDE + m0;
        *(float4*)op       = o1;
        *(float4*)(op + 4) = o2;
    }
}

extern "C" void kernel_launch(void* const* d_in, const int* in_sizes, int n_in,
                              void* d_out, int out_size, void* d_ws, size_t ws_size,
                              hipStream_t stream) {
    const float* q = (const float*)d_in[0];
    const float* k = (const float*)d_in[1];
    const float* v = (const float*)d_in[2];
    float* out = (float*)d_out;

    // pick chunk count (one wave per chunk) that fits workspace
    int nchunk = 64;
    while (nchunk > 4) {
        size_t need = ((size_t)NH * nchunk * (D_DIM * D_DIM + D_DIM)
                       + (size_t)NH * (D_DIM * D_DIM + D_DIM)) * sizeof(float);
        if (need <= ws_size) break;
        nchunk >>= 1;
    }

    float* kvp  = (float*)d_ws;
    float* ksp  = kvp + (size_t)NH * nchunk * D_DIM * D_DIM;
    float* KVf  = ksp + (size_t)NH * nchunk * D_DIM;
    float* Ksum = KVf + (size_t)NH * D_DIM * D_DIM;

    kv_partial_kernel<<<NH * nchunk / 4, 256, 0, stream>>>(k, v, kvp, ksp, nchunk);
    kv_reduce_kernel<<<NH * 16, 256, 0, stream>>>(kvp, ksp, KVf, Ksum, nchunk);
    out_kernel<<<NH * (S_LEN / 128), 256, 0, stream>>>(q, KVf, Ksum, out);
}

// Round 3
// 236.246 us; speedup vs baseline: 1.4367x; 1.4367x over previous
//
#include <hip/hip_runtime.h>
#include <math.h>

// LinearAttention: out[n,l,h,m] = (phi(Q[l])·KV[:,m]) / (phi(Q[l])·Ksum + eps)
//   KV[d][m] = sum_s phi(K[s,d]) V[s,m],  Ksum[d] = sum_s phi(K[s,d])
//   phi(x) = elu(x)+1 = x>0 ? x+1 : exp(x)

#define N_B 8
#define S_LEN 8192
#define H_N 8
#define D_DIM 64
#define NH (N_B * H_N)
#define EPS 1e-6f
#define ROWSTRIDE (H_N * D_DIM)   // 512 floats between consecutive s rows
#define NCHUNK 16
#define TS 32                      // rows per LDS tile
#define TILES (S_LEN / NCHUNK / TS) // 16 tiles per block

__device__ __forceinline__ float felu1(float x) {
    return x > 0.0f ? x + 1.0f : __expf(x);
}

__device__ __forceinline__ void gload_lds16(const float* g, float* lds_base) {
    __builtin_amdgcn_global_load_lds(
        (const __attribute__((address_space(1))) unsigned int*)g,
        (__attribute__((address_space(3))) unsigned int*)lds_base, 16, 0, 0);
}

// ---------------- Phase 1a: block per (nh, chunk) ----------------
// 4 waves x 8 rows each, 8x8 register tile per lane, double-buffered LDS,
// one barrier per 32-row tile. V staged via global_load_lds (no transform);
// K staged via regs (phi applied, Ksum accumulated during staging).
__global__ __launch_bounds__(256, 4) void kv_partial_kernel(
        const float* __restrict__ Kin, const float* __restrict__ Vin,
        float* __restrict__ kvp,   // [NH*NCHUNK][64*64]
        float* __restrict__ ksp) { // [NH*NCHUNK][64]
    __shared__ __align__(16) float Ks[2][TS][D_DIM];  // 16 KB
    __shared__ __align__(16) float Vs[2][TS][D_DIM];  // 16 KB

    const int b  = blockIdx.x;
    const int nh = b / NCHUNK;
    const int c  = b - nh * NCHUNK;
    const int n_i = nh >> 3, h_i = nh & 7;
    const int s0  = c * (S_LEN / NCHUNK);

    const int t = threadIdx.x;
    const int w = t >> 6;        // wave 0..3
    const int l = t & 63;        // lane
    const int d8 = l >> 3;       // 0..7 -> d rows d8*8..+7
    const int m8 = l & 7;        // 0..7 -> m cols m8*8..+7

    const float* Kb = Kin + (size_t)n_i * S_LEN * ROWSTRIDE + (size_t)h_i * D_DIM;
    const float* Vb = Vin + (size_t)n_i * S_LEN * ROWSTRIDE + (size_t)h_i * D_DIM;

    float acc[8][8];
    #pragma unroll
    for (int i = 0; i < 8; ++i)
        #pragma unroll
        for (int j = 0; j < 8; ++j) acc[i][j] = 0.0f;
    float ksphi[8];
    #pragma unroll
    for (int i = 0; i < 8; ++i) ksphi[i] = 0.0f;

    // staging roles: K -> row w*8 + (l>>3), cols (l&7)*8..+7 (phi'd, ksum'd)
    //                V -> global_load_lds, 1KB (4 rows) per instr, 2 per wave
    const int krow = w * 8 + (l >> 3);
    const int kcol = (l & 7) * 8;

    #define STAGE(buf, tile)                                                     \
    {                                                                            \
        const int sr = s0 + (tile) * TS;                                         \
        /* V: two 1KB global_load_lds per wave (rows w*8+j*4 .. +3) */           \
        _Pragma("unroll")                                                        \
        for (int j = 0; j < 2; ++j) {                                            \
            const float* gp = Vb + (size_t)(sr + w * 8 + j * 4 + (l >> 4)) *     \
                              ROWSTRIDE + (l & 15) * 4;                          \
            gload_lds16(gp, &Vs[buf][w * 8 + j * 4][0]);                         \
        }                                                                        \
        /* K: 8 floats -> phi -> LDS, fold into ksum */                          \
        const float* kp = Kb + (size_t)(sr + krow) * ROWSTRIDE + kcol;           \
        const float4 a = *(const float4*)kp;                                     \
        const float4 bq = *(const float4*)(kp + 4);                              \
        float4 fa, fb;                                                           \
        fa.x = felu1(a.x);  fa.y = felu1(a.y);                                   \
        fa.z = felu1(a.z);  fa.w = felu1(a.w);                                   \
        fb.x = felu1(bq.x); fb.y = felu1(bq.y);                                  \
        fb.z = felu1(bq.z); fb.w = felu1(bq.w);                                  \
        ksphi[0] += fa.x; ksphi[1] += fa.y; ksphi[2] += fa.z; ksphi[3] += fa.w;  \
        ksphi[4] += fb.x; ksphi[5] += fb.y; ksphi[6] += fb.z; ksphi[7] += fb.w;  \
        *(float4*)&Ks[buf][krow][kcol]     = fa;                                 \
        *(float4*)&Ks[buf][krow][kcol + 4] = fb;                                 \
    }

    STAGE(0, 0)
    __syncthreads();

    int cur = 0;
    for (int tile = 0; tile < TILES; ++tile) {
        if (tile + 1 < TILES) STAGE(cur ^ 1, tile + 1)
        // compute: this wave's 8 rows of the staged tile
        #pragma unroll
        for (int rr = 0; rr < 8; ++rr) {
            const int r = w * 8 + rr;
            const float4 k0 = *(const float4*)&Ks[cur][r][d8 * 8];
            const float4 k1 = *(const float4*)&Ks[cur][r][d8 * 8 + 4];
            const float4 v0 = *(const float4*)&Vs[cur][r][m8 * 8];
            const float4 v1 = *(const float4*)&Vs[cur][r][m8 * 8 + 4];
            const float ka[8] = {k0.x, k0.y, k0.z, k0.w, k1.x, k1.y, k1.z, k1.w};
            const float va[8] = {v0.x, v0.y, v0.z, v0.w, v1.x, v1.y, v1.z, v1.w};
            #pragma unroll
            for (int i = 0; i < 8; ++i)
                #pragma unroll
                for (int j = 0; j < 8; ++j)
                    acc[i][j] += ka[i] * va[j];
        }
        __syncthreads();
        cur ^= 1;
    }

    // ---- cross-wave merge in LDS (reuse staging buffers) ----
    float* L0  = &Ks[0][0][0];   // 4096 floats
    float* L1  = &Vs[0][0][0];   // 4096 floats
    float* KSL = L1;             // [32][64] after L1 is consumed

    // S1: waves 1,3 dump acc
    if (w == 1 || w == 3) {
        float* L = (w == 1) ? L0 : L1;
        #pragma unroll
        for (int i = 0; i < 8; ++i) {
            float* p = L + (d8 * 8 + i) * 64 + m8 * 8;
            *(float4*)p       = make_float4(acc[i][0], acc[i][1], acc[i][2], acc[i][3]);
            *(float4*)(p + 4) = make_float4(acc[i][4], acc[i][5], acc[i][6], acc[i][7]);
        }
    }
    __syncthreads();
    // S2: waves 0,2 absorb
    if (w == 0 || w == 2) {
        const float* L = (w == 0) ? L0 : L1;
        #pragma unroll
        for (int i = 0; i < 8; ++i) {
            const float* p = L + (d8 * 8 + i) * 64 + m8 * 8;
            const float4 x = *(const float4*)p;
            const float4 y = *(const float4*)(p + 4);
            acc[i][0] += x.x; acc[i][1] += x.y; acc[i][2] += x.z; acc[i][3] += x.w;
            acc[i][4] += y.x; acc[i][5] += y.y; acc[i][6] += y.z; acc[i][7] += y.w;
        }
    }
    __syncthreads();
    // S3: wave 2 dumps merged acc; everyone dumps ksphi
    if (w == 2) {
        #pragma unroll
        for (int i = 0; i < 8; ++i) {
            float* p = L0 + (d8 * 8 + i) * 64 + m8 * 8;
            *(float4*)p       = make_float4(acc[i][0], acc[i][1], acc[i][2], acc[i][3]);
            *(float4*)(p + 4) = make_float4(acc[i][4], acc[i][5], acc[i][6], acc[i][7]);
        }
    }
    {
        float* p = KSL + krow * 64 + kcol;
        *(float4*)p       = make_float4(ksphi[0], ksphi[1], ksphi[2], ksphi[3]);
        *(float4*)(p + 4) = make_float4(ksphi[4], ksphi[5], ksphi[6], ksphi[7]);
    }
    __syncthreads();
    // S4: wave 0 finalizes
    if (w == 0) {
        float* kvo = kvp + (size_t)b * (D_DIM * D_DIM);
        #pragma unroll
        for (int i = 0; i < 8; ++i) {
            const float* p = L0 + (d8 * 8 + i) * 64 + m8 * 8;
            const float4 x = *(const float4*)p;
            const float4 y = *(const float4*)(p + 4);
            float4 o1, o2;
            o1.x = acc[i][0] + x.x; o1.y = acc[i][1] + x.y;
            o1.z = acc[i][2] + x.z; o1.w = acc[i][3] + x.w;
            o2.x = acc[i][4] + y.x; o2.y = acc[i][5] + y.y;
            o2.z = acc[i][6] + y.z; o2.w = acc[i][7] + y.w;
            float* q = kvo + (d8 * 8 + i) * 64 + m8 * 8;
            *(float4*)q       = o1;
            *(float4*)(q + 4) = o2;
        }
    }
    if (t < D_DIM) {
        float s = 0.0f;
        #pragma unroll
        for (int r = 0; r < 32; ++r) s += KSL[r * 64 + t];
        ksp[(size_t)b * D_DIM + t] = s;
    }
    #undef STAGE
}

// ---------------- Phase 1b: reduce partials -> final KV, Ksum ----------------
__global__ __launch_bounds__(256) void kv_reduce_kernel(
        const float* __restrict__ kvp, const float* __restrict__ ksp,
        float* __restrict__ KV, float* __restrict__ Ksum) {
    const int nh = blockIdx.x >> 4;
    const int eb = blockIdx.x & 15;
    const int t  = threadIdx.x;
    const int e  = eb * 256 + t;
    float s = 0.0f;
    const float* base = kvp + (size_t)nh * NCHUNK * (D_DIM * D_DIM) + e;
    #pragma unroll
    for (int c = 0; c < NCHUNK; ++c)
        s += base[(size_t)c * (D_DIM * D_DIM)];
    KV[(size_t)nh * (D_DIM * D_DIM) + e] = s;
    if (eb == 0 && t < D_DIM) {
        float ks = 0.0f;
        const float* kb = ksp + (size_t)nh * NCHUNK * D_DIM + t;
        #pragma unroll
        for (int c = 0; c < NCHUNK; ++c) ks += kb[(size_t)c * D_DIM];
        Ksum[(size_t)nh * D_DIM + t] = ks;
    }
}

// ---------------- Phase 2: out = (Q·KV) / (Q·Ksum + eps) ----------------
// 256 threads: thread = (rg = t>>3 -> 4 rows, mg = t&7 -> 8 m). RPB=128 rows.
__global__ __launch_bounds__(256) void out_kernel(
        const float* __restrict__ Qin, const float* __restrict__ KV,
        const float* __restrict__ Ksum, float* __restrict__ Out) {
    constexpr int RPB  = 128;
    constexpr int QPAD = 68;
    __shared__ __align__(16) float KVs[D_DIM][D_DIM];   // 16 KB
    __shared__ __align__(16) float Kss[D_DIM];
    __shared__ __align__(16) float Qs[RPB][QPAD];       // 34.8 KB, XOR-swizzled cols

    const int b    = blockIdx.x;
    const int nblk = S_LEN / RPB;          // 64
    const int nh   = b / nblk;
    const int rb   = b - nh * nblk;
    const int n_i  = nh >> 3, h_i = nh & 7;
    const int t    = threadIdx.x;

    const float* Qb = Qin + (size_t)n_i * S_LEN * ROWSTRIDE + (size_t)h_i * D_DIM;
    float*       Ob = Out + (size_t)n_i * S_LEN * ROWSTRIDE + (size_t)h_i * D_DIM;

    {
        const float4* src = (const float4*)(KV + (size_t)nh * (D_DIM * D_DIM));
        float4* dst = (float4*)(&KVs[0][0]);
        #pragma unroll
        for (int i = 0; i < 4; ++i) dst[t + 256 * i] = src[t + 256 * i];
        if (t < 16) ((float4*)Kss)[t] = ((const float4*)(Ksum + (size_t)nh * D_DIM))[t];
    }

    const int ltx = t & 15, lty = t >> 4;
    const int sbase = rb * RPB;
    #pragma unroll
    for (int i = 0; i < 8; ++i) {
        const int row = lty + 16 * i;
        const float4 q = *(const float4*)(Qb + (size_t)(sbase + row) * ROWSTRIDE + ltx * 4);
        float4 f;
        f.x = felu1(q.x); f.y = felu1(q.y); f.z = felu1(q.z); f.w = felu1(q.w);
        const int pc = (ltx * 4) ^ (((row >> 2) & 7) << 2);
        *(float4*)&Qs[row][pc] = f;
    }
    __syncthreads();

    const int rg = t >> 3;                 // 0..31 -> rows rg*4..rg*4+3
    const int mg = t & 7;                  // 0..7  -> cols mg*8..mg*8+7
    const int r0 = rg * 4, m0 = mg * 8;
    const int sw = ((rg & 7) << 2);

    float acc[4][8];
    float zz[4];
    #pragma unroll
    for (int r = 0; r < 4; ++r) {
        zz[r] = 0.0f;
        #pragma unroll
        for (int m = 0; m < 8; ++m) acc[r][m] = 0.0f;
    }

    #pragma unroll
    for (int d0 = 0; d0 < D_DIM; d0 += 4) {
        const float4 ks4 = *(const float4*)&Kss[d0];
        float4 qr[4];
        #pragma unroll
        for (int r = 0; r < 4; ++r) {
            qr[r] = *(const float4*)&Qs[r0 + r][d0 ^ sw];
            zz[r] += qr[r].x * ks4.x + qr[r].y * ks4.y
                   + qr[r].z * ks4.z + qr[r].w * ks4.w;
        }
        #pragma unroll
        for (int j = 0; j < 4; ++j) {
            const float4 kva = *(const float4*)&KVs[d0 + j][m0];
            const float4 kvb = *(const float4*)&KVs[d0 + j][m0 + 4];
            #pragma unroll
            for (int r = 0; r < 4; ++r) {
                const float q = (&qr[r].x)[j];
                acc[r][0] += q * kva.x; acc[r][1] += q * kva.y;
                acc[r][2] += q * kva.z; acc[r][3] += q * kva.w;
                acc[r][4] += q * kvb.x; acc[r][5] += q * kvb.y;
                acc[r][6] += q * kvb.z; acc[r][7] += q * kvb.w;
            }
        }
    }

    #pragma unroll
    for (int r = 0; r < 4; ++r) {
        const float z = 1.0f / (zz[r] + EPS);
        float4 o1, o2;
        o1.x = acc[r][0] * z; o1.y = acc[r][1] * z;
        o1.z = acc[r][2] * z; o1.w = acc[r][3] * z;
        o2.x = acc[r][4] * z; o2.y = acc[r][5] * z;
        o2.z = acc[r][6] * z; o2.w = acc[r][7] * z;
        float* op = Ob + (size_t)(sbase + r0 + r) * ROWSTRIDE + m0;
        *(float4*)op       = o1;
        *(float4*)(op + 4) = o2;
    }
}

extern "C" void kernel_launch(void* const* d_in, const int* in_sizes, int n_in,
                              void* d_out, int out_size, void* d_ws, size_t ws_size,
                              hipStream_t stream) {
    const float* q = (const float*)d_in[0];
    const float* k = (const float*)d_in[1];
    const float* v = (const float*)d_in[2];
    float* out = (float*)d_out;

    float* kvp  = (float*)d_ws;
    float* ksp  = kvp + (size_t)NH * NCHUNK * D_DIM * D_DIM;
    float* KVf  = ksp + (size_t)NH * NCHUNK * D_DIM;
    float* Ksum = KVf + (size_t)NH * D_DIM * D_DIM;

    kv_partial_kernel<<<NH * NCHUNK, 256, 0, stream>>>(k, v, kvp, ksp);
    kv_reduce_kernel<<<NH * 16, 256, 0, stream>>>(kvp, ksp, KVf, Ksum);
    out_kernel<<<NH * (S_LEN / 128), 256, 0, stream>>>(q, KVf, Ksum, out);
}

// Round 4
// 181.934 us; speedup vs baseline: 1.8656x; 1.2985x over previous
//
#include <hip/hip_runtime.h>
#include <math.h>

// LinearAttention: out[n,l,h,m] = (phi(Q[l])·KV[:,m]) / (phi(Q[l])·Ksum + eps)
//   KV[d][m] = sum_s phi(K[s,d]) V[s,m],  Ksum[d] = sum_s phi(K[s,d])
//   phi(x) = elu(x)+1 = x>0 ? x+1 : exp(x)

#define N_B 8
#define S_LEN 8192
#define H_N 8
#define D_DIM 64
#define NH (N_B * H_N)
#define EPS 1e-6f
#define ROWSTRIDE (H_N * D_DIM)   // 512 floats between consecutive s rows
#define NCHUNK 16
#define TS 32                      // rows per LDS tile
#define TILES (S_LEN / NCHUNK / TS) // 16 tiles per block
#define KPAD 68                    // padded K-tile row stride (banks rotate 4/row)

__device__ __forceinline__ float felu1(float x) {
    return x > 0.0f ? x + 1.0f : __expf(x);
}

__device__ __forceinline__ void gload_lds16(const float* g, float* lds_base) {
    __builtin_amdgcn_global_load_lds(
        (const __attribute__((address_space(1))) unsigned int*)g,
        (__attribute__((address_space(3))) unsigned int*)lds_base, 16, 0, 0);
}

// ---------------- Phase 1a: block per (nh, chunk) ----------------
// 4 waves x 8 rows each, 8x8 register tile per lane, double-buffered LDS,
// one barrier per 32-row tile. V staged via global_load_lds (linear layout);
// K staged via regs (phi applied, per-thread column partials for Ksum).
// No launch_bounds min-waves: let the allocator keep the 64-float acc live.
__global__ __launch_bounds__(256) void kv_partial_kernel(
        const float* __restrict__ Kin, const float* __restrict__ Vin,
        float* __restrict__ kvp,   // [NH*NCHUNK][64*64]
        float* __restrict__ ksp) { // [NH*NCHUNK][64]
    __shared__ __align__(16) float Ks[2][TS][KPAD];  // 17.4 KB
    __shared__ __align__(16) float Vs[2][TS][D_DIM]; // 16.4 KB (linear)

    const int b  = blockIdx.x;
    const int nh = b / NCHUNK;
    const int c  = b - nh * NCHUNK;
    const int n_i = nh >> 3, h_i = nh & 7;
    const int s0  = c * (S_LEN / NCHUNK);

    const int t = threadIdx.x;
    const int w = t >> 6;        // wave 0..3
    const int l = t & 63;        // lane
    const int d8 = l >> 3;       // 0..7 -> d rows d8*8..+7
    const int m8 = l & 7;        // 0..7 -> m cols m8*8..+7

    const float* Kb = Kin + (size_t)n_i * S_LEN * ROWSTRIDE + (size_t)h_i * D_DIM;
    const float* Vb = Vin + (size_t)n_i * S_LEN * ROWSTRIDE + (size_t)h_i * D_DIM;

    float acc[8][8];
    #pragma unroll
    for (int i = 0; i < 8; ++i)
        #pragma unroll
        for (int j = 0; j < 8; ++j) acc[i][j] = 0.0f;
    float ksphi[8];
    #pragma unroll
    for (int i = 0; i < 8; ++i) ksphi[i] = 0.0f;

    // staging roles: thread t -> K row t>>3 (0..31), cols (t&7)*8..+7
    const int srow = t >> 3;
    const int scol = (t & 7) * 8;

    auto stage = [&](int buf, int tile) {
        const int sr = s0 + tile * TS;
        // V: two 1KB global_load_lds per wave (rows w*8+j*4+(l>>4), 16B/lane)
        #pragma unroll
        for (int j = 0; j < 2; ++j) {
            const float* gp = Vb + (size_t)(sr + w * 8 + j * 4 + (l >> 4)) * ROWSTRIDE
                            + (l & 15) * 4;
            gload_lds16(gp, &Vs[buf][w * 8 + j * 4][0]);
        }
        // K: 8 floats -> phi -> padded LDS row, fold into column partials
        const float* kp = Kb + (size_t)(sr + srow) * ROWSTRIDE + scol;
        const float4 a  = *(const float4*)kp;
        const float4 b2 = *(const float4*)(kp + 4);
        float4 fa, fb;
        fa.x = felu1(a.x);  fa.y = felu1(a.y);
        fa.z = felu1(a.z);  fa.w = felu1(a.w);
        fb.x = felu1(b2.x); fb.y = felu1(b2.y);
        fb.z = felu1(b2.z); fb.w = felu1(b2.w);
        ksphi[0] += fa.x; ksphi[1] += fa.y; ksphi[2] += fa.z; ksphi[3] += fa.w;
        ksphi[4] += fb.x; ksphi[5] += fb.y; ksphi[6] += fb.z; ksphi[7] += fb.w;
        *(float4*)&Ks[buf][srow][scol]     = fa;
        *(float4*)&Ks[buf][srow][scol + 4] = fb;
    };

    stage(0, 0);
    __syncthreads();

    int cur = 0;
    for (int tile = 0; tile < TILES; ++tile) {
        if (tile + 1 < TILES) stage(cur ^ 1, tile + 1);
        #pragma unroll
        for (int rr = 0; rr < 8; ++rr) {
            const int r = w * 8 + rr;
            const float4 k0 = *(const float4*)&Ks[cur][r][d8 * 8];
            const float4 k1 = *(const float4*)&Ks[cur][r][d8 * 8 + 4];
            const float4 v0 = *(const float4*)&Vs[cur][r][m8 * 8];
            const float4 v1 = *(const float4*)&Vs[cur][r][m8 * 8 + 4];
            acc[0][0] += k0.x*v0.x; acc[0][1] += k0.x*v0.y; acc[0][2] += k0.x*v0.z; acc[0][3] += k0.x*v0.w;
            acc[0][4] += k0.x*v1.x; acc[0][5] += k0.x*v1.y; acc[0][6] += k0.x*v1.z; acc[0][7] += k0.x*v1.w;
            acc[1][0] += k0.y*v0.x; acc[1][1] += k0.y*v0.y; acc[1][2] += k0.y*v0.z; acc[1][3] += k0.y*v0.w;
            acc[1][4] += k0.y*v1.x; acc[1][5] += k0.y*v1.y; acc[1][6] += k0.y*v1.z; acc[1][7] += k0.y*v1.w;
            acc[2][0] += k0.z*v0.x; acc[2][1] += k0.z*v0.y; acc[2][2] += k0.z*v0.z; acc[2][3] += k0.z*v0.w;
            acc[2][4] += k0.z*v1.x; acc[2][5] += k0.z*v1.y; acc[2][6] += k0.z*v1.z; acc[2][7] += k0.z*v1.w;
            acc[3][0] += k0.w*v0.x; acc[3][1] += k0.w*v0.y; acc[3][2] += k0.w*v0.z; acc[3][3] += k0.w*v0.w;
            acc[3][4] += k0.w*v1.x; acc[3][5] += k0.w*v1.y; acc[3][6] += k0.w*v1.z; acc[3][7] += k0.w*v1.w;
            acc[4][0] += k1.x*v0.x; acc[4][1] += k1.x*v0.y; acc[4][2] += k1.x*v0.z; acc[4][3] += k1.x*v0.w;
            acc[4][4] += k1.x*v1.x; acc[4][5] += k1.x*v1.y; acc[4][6] += k1.x*v1.z; acc[4][7] += k1.x*v1.w;
            acc[5][0] += k1.y*v0.x; acc[5][1] += k1.y*v0.y; acc[5][2] += k1.y*v0.z; acc[5][3] += k1.y*v0.w;
            acc[5][4] += k1.y*v1.x; acc[5][5] += k1.y*v1.y; acc[5][6] += k1.y*v1.z; acc[5][7] += k1.y*v1.w;
            acc[6][0] += k1.z*v0.x; acc[6][1] += k1.z*v0.y; acc[6][2] += k1.z*v0.z; acc[6][3] += k1.z*v0.w;
            acc[6][4] += k1.z*v1.x; acc[6][5] += k1.z*v1.y; acc[6][6] += k1.z*v1.z; acc[6][7] += k1.z*v1.w;
            acc[7][0] += k1.w*v0.x; acc[7][1] += k1.w*v0.y; acc[7][2] += k1.w*v0.z; acc[7][3] += k1.w*v0.w;
            acc[7][4] += k1.w*v1.x; acc[7][5] += k1.w*v1.y; acc[7][6] += k1.w*v1.z; acc[7][7] += k1.w*v1.w;
        }
        __syncthreads();
        cur ^= 1;
    }

    // ---- cross-wave merge in LDS (reuse staging buffers as flat scratch) ----
    float* L0  = &Ks[0][0][0];   // >= 4096 floats
    float* L1  = &Vs[0][0][0];   // 4096 floats
    float* KSL = L1;             // [32][64] reused after L1 consumed

    if (w == 1 || w == 3) {
        float* L = (w == 1) ? L0 : L1;
        #pragma unroll
        for (int i = 0; i < 8; ++i) {
            float* p = L + (d8 * 8 + i) * 64 + m8 * 8;
            *(float4*)p       = make_float4(acc[i][0], acc[i][1], acc[i][2], acc[i][3]);
            *(float4*)(p + 4) = make_float4(acc[i][4], acc[i][5], acc[i][6], acc[i][7]);
        }
    }
    __syncthreads();
    if (w == 0 || w == 2) {
        const float* L = (w == 0) ? L0 : L1;
        #pragma unroll
        for (int i = 0; i < 8; ++i) {
            const float* p = L + (d8 * 8 + i) * 64 + m8 * 8;
            const float4 x = *(const float4*)p;
            const float4 y = *(const float4*)(p + 4);
            acc[i][0] += x.x; acc[i][1] += x.y; acc[i][2] += x.z; acc[i][3] += x.w;
            acc[i][4] += y.x; acc[i][5] += y.y; acc[i][6] += y.z; acc[i][7] += y.w;
        }
    }
    __syncthreads();
    if (w == 2) {
        #pragma unroll
        for (int i = 0; i < 8; ++i) {
            float* p = L0 + (d8 * 8 + i) * 64 + m8 * 8;
            *(float4*)p       = make_float4(acc[i][0], acc[i][1], acc[i][2], acc[i][3]);
            *(float4*)(p + 4) = make_float4(acc[i][4], acc[i][5], acc[i][6], acc[i][7]);
        }
    }
    {
        float* p = KSL + srow * 64 + scol;
        *(float4*)p       = make_float4(ksphi[0], ksphi[1], ksphi[2], ksphi[3]);
        *(float4*)(p + 4) = make_float4(ksphi[4], ksphi[5], ksphi[6], ksphi[7]);
    }
    __syncthreads();
    if (w == 0) {
        float* kvo = kvp + (size_t)b * (D_DIM * D_DIM);
        #pragma unroll
        for (int i = 0; i < 8; ++i) {
            const float* p = L0 + (d8 * 8 + i) * 64 + m8 * 8;
            const float4 x = *(const float4*)p;
            const float4 y = *(const float4*)(p + 4);
            float4 o1, o2;
            o1.x = acc[i][0] + x.x; o1.y = acc[i][1] + x.y;
            o1.z = acc[i][2] + x.z; o1.w = acc[i][3] + x.w;
            o2.x = acc[i][4] + y.x; o2.y = acc[i][5] + y.y;
            o2.z = acc[i][6] + y.z; o2.w = acc[i][7] + y.w;
            float* q = kvo + (d8 * 8 + i) * 64 + m8 * 8;
            *(float4*)q       = o1;
            *(float4*)(q + 4) = o2;
        }
    }
    if (t < D_DIM) {
        float s = 0.0f;
        #pragma unroll
        for (int r = 0; r < 32; ++r) s += KSL[r * 64 + t];
        ksp[(size_t)b * D_DIM + t] = s;
    }
}

// ---------------- Phase 1b: reduce partials -> final KV, Ksum ----------------
__global__ __launch_bounds__(256) void kv_reduce_kernel(
        const float* __restrict__ kvp, const float* __restrict__ ksp,
        float* __restrict__ KV, float* __restrict__ Ksum) {
    const int nh = blockIdx.x >> 4;
    const int eb = blockIdx.x & 15;
    const int t  = threadIdx.x;
    const int e  = eb * 256 + t;
    float s = 0.0f;
    const float* base = kvp + (size_t)nh * NCHUNK * (D_DIM * D_DIM) + e;
    #pragma unroll
    for (int c = 0; c < NCHUNK; ++c)
        s += base[(size_t)c * (D_DIM * D_DIM)];
    KV[(size_t)nh * (D_DIM * D_DIM) + e] = s;
    if (eb == 0 && t < D_DIM) {
        float ks = 0.0f;
        const float* kb = ksp + (size_t)nh * NCHUNK * D_DIM + t;
        #pragma unroll
        for (int c = 0; c < NCHUNK; ++c) ks += kb[(size_t)c * D_DIM];
        Ksum[(size_t)nh * D_DIM + t] = ks;
    }
}

// ---------------- Phase 2: out = (Q·KV) / (Q·Ksum + eps) ----------------
__global__ __launch_bounds__(256) void out_kernel(
        const float* __restrict__ Qin, const float* __restrict__ KV,
        const float* __restrict__ Ksum, float* __restrict__ Out) {
    constexpr int RPB  = 128;
    constexpr int QPAD = 68;
    __shared__ __align__(16) float KVs[D_DIM][D_DIM];   // 16 KB
    __shared__ __align__(16) float Kss[D_DIM];
    __shared__ __align__(16) float Qs[RPB][QPAD];       // 34.8 KB, XOR-swizzled cols

    const int b    = blockIdx.x;
    const int nblk = S_LEN / RPB;          // 64
    const int nh   = b / nblk;
    const int rb   = b - nh * nblk;
    const int n_i  = nh >> 3, h_i = nh & 7;
    const int t    = threadIdx.x;

    const float* Qb = Qin + (size_t)n_i * S_LEN * ROWSTRIDE + (size_t)h_i * D_DIM;
    float*       Ob = Out + (size_t)n_i * S_LEN * ROWSTRIDE + (size_t)h_i * D_DIM;

    {
        const float4* src = (const float4*)(KV + (size_t)nh * (D_DIM * D_DIM));
        float4* dst = (float4*)(&KVs[0][0]);
        #pragma unroll
        for (int i = 0; i < 4; ++i) dst[t + 256 * i] = src[t + 256 * i];
        if (t < 16) ((float4*)Kss)[t] = ((const float4*)(Ksum + (size_t)nh * D_DIM))[t];
    }

    const int ltx = t & 15, lty = t >> 4;
    const int sbase = rb * RPB;
    #pragma unroll
    for (int i = 0; i < 8; ++i) {
        const int row = lty + 16 * i;
        const float4 q = *(const float4*)(Qb + (size_t)(sbase + row) * ROWSTRIDE + ltx * 4);
        float4 f;
        f.x = felu1(q.x); f.y = felu1(q.y); f.z = felu1(q.z); f.w = felu1(q.w);
        const int pc = (ltx * 4) ^ (((row >> 2) & 7) << 2);
        *(float4*)&Qs[row][pc] = f;
    }
    __syncthreads();

    const int rg = t >> 3;                 // 0..31 -> rows rg*4..rg*4+3
    const int mg = t & 7;                  // 0..7  -> cols mg*8..mg*8+7
    const int r0 = rg * 4, m0 = mg * 8;
    const int sw = ((rg & 7) << 2);

    float acc[4][8];
    float zz[4];
    #pragma unroll
    for (int r = 0; r < 4; ++r) {
        zz[r] = 0.0f;
        #pragma unroll
        for (int m = 0; m < 8; ++m) acc[r][m] = 0.0f;
    }

    #pragma unroll
    for (int d0 = 0; d0 < D_DIM; d0 += 4) {
        const float4 ks4 = *(const float4*)&Kss[d0];
        float4 qr[4];
        #pragma unroll
        for (int r = 0; r < 4; ++r) {
            qr[r] = *(const float4*)&Qs[r0 + r][d0 ^ sw];
            zz[r] += qr[r].x * ks4.x + qr[r].y * ks4.y
                   + qr[r].z * ks4.z + qr[r].w * ks4.w;
        }
        #pragma unroll
        for (int j = 0; j < 4; ++j) {
            const float4 kva = *(const float4*)&KVs[d0 + j][m0];
            const float4 kvb = *(const float4*)&KVs[d0 + j][m0 + 4];
            #pragma unroll
            for (int r = 0; r < 4; ++r) {
                const float q = (&qr[r].x)[j];
                acc[r][0] += q * kva.x; acc[r][1] += q * kva.y;
                acc[r][2] += q * kva.z; acc[r][3] += q * kva.w;
                acc[r][4] += q * kvb.x; acc[r][5] += q * kvb.y;
                acc[r][6] += q * kvb.z; acc[r][7] += q * kvb.w;
            }
        }
    }

    #pragma unroll
    for (int r = 0; r < 4; ++r) {
        const float z = 1.0f / (zz[r] + EPS);
        float4 o1, o2;
        o1.x = acc[r][0] * z; o1.y = acc[r][1] * z;
        o1.z = acc[r][2] * z; o1.w = acc[r][3] * z;
        o2.x = acc[r][4] * z; o2.y = acc[r][5] * z;
        o2.z = acc[r][6] * z; o2.w = acc[r][7] * z;
        float* op = Ob + (size_t)(sbase + r0 + r) * ROWSTRIDE + m0;
        *(float4*)op       = o1;
        *(float4*)(op + 4) = o2;
    }
}

extern "C" void kernel_launch(void* const* d_in, const int* in_sizes, int n_in,
                              void* d_out, int out_size, void* d_ws, size_t ws_size,
                              hipStream_t stream) {
    const float* q = (const float*)d_in[0];
    const float* k = (const float*)d_in[1];
    const float* v = (const float*)d_in[2];
    float* out = (float*)d_out;

    float* kvp  = (float*)d_ws;
    float* ksp  = kvp + (size_t)NH * NCHUNK * D_DIM * D_DIM;
    float* KVf  = ksp + (size_t)NH * NCHUNK * D_DIM;
    float* Ksum = KVf + (size_t)NH * D_DIM * D_DIM;

    kv_partial_kernel<<<NH * NCHUNK, 256, 0, stream>>>(k, v, kvp, ksp);
    kv_reduce_kernel<<<NH * 16, 256, 0, stream>>>(kvp, ksp, KVf, Ksum);
    out_kernel<<<NH * (S_LEN / 128), 256, 0, stream>>>(q, KVf, Ksum, out);
}